// Round 12
// baseline (396.489 us; speedup 1.0000x reference)
//
#include <hip/hip_runtime.h>
#include <math.h>
#include <stdint.h>

#define N_NODES 100000
#define N_EDGES 3200000
#define IN_DIM  64
#define HID     16
#define OUTD    2

#define NPAD     100352                // N padded (multiple of 1024)
#define B_CHUNKS 128                   // edge chunks
#define CHUNK_E  (N_EDGES / B_CHUNKS)  // 25000 edges per chunk
#define NB       512                   // dst buckets
#define BK_NODES (NPAD / NB)           // 196 nodes per bucket
#define BK_CAP   7680                  // mean 6250 + ~18 sigma, LDS cap

// workspace layout (float offsets) — ~31 MB
#define OFF_DINV  0
#define OFF_RS    (OFF_DINV + NPAD)
#define OFF_RE    (OFF_RS + NPAD)
#define OFF_H1B   (OFF_RE + NPAD)            // bf16x2-packed h1s [N][8] u32 (3.2 MB)
#define OFF_H2    (OFF_H1B + N_NODES * 8)    // h2s = dinv[n]*h2raw  [N,2] fp32
#define OFF_CSR   (OFF_H2 + N_NODES * OUTD)  // CSR src ids [E]
#define OFF_PAIRS (OFF_CSR + N_EDGES)        // u32 (src<<8 | dst_local) [E]
#define OFF_HCNT  (OFF_PAIRS + N_EDGES)      // u32 [B_CHUNKS][NB]
#define OFF_BST   (OFF_HCNT + B_CHUNKS * NB) // int [NB+1]

__device__ __forceinline__ unsigned packbf2(float f0, float f1) {
    unsigned a = __float_as_uint(f0), b = __float_as_uint(f1);
    a = (a + 0x7fffu + ((a >> 16) & 1u)) >> 16;          // RNE
    b = (b + 0x7fffu + ((b >> 16) & 1u)) >> 16;
    return a | (b << 16);
}

// ---- CSR build: zero global atomics, ~1x write amplification --------------

__global__ __launch_bounds__(256) void k_bhist(const int* __restrict__ dst,
                                               unsigned* __restrict__ hcnt) {
    __shared__ unsigned h[NB];
    for (int i = threadIdx.x; i < NB; i += 256) h[i] = 0u;
    __syncthreads();
    int base = blockIdx.x * CHUNK_E;
    for (int i = threadIdx.x; i < CHUNK_E; i += 256)
        atomicAdd(&h[dst[base + i] / BK_NODES], 1u);
    __syncthreads();
    for (int i = threadIdx.x; i < NB; i += 256)
        hcnt[(size_t)blockIdx.x * NB + i] = h[i];
}

// bucket starts + in-place chunk-prefix: hcnt[b][bk] -> absolute run base
__global__ __launch_bounds__(512) void k_bscan(unsigned* __restrict__ hcnt,
                                               int* __restrict__ bstart) {
    int bk = threadIdx.x, lane = bk & 63, wid = bk >> 6;
    int tot = 0;
    for (int b = 0; b < B_CHUNKS; b++) tot += (int)hcnt[(size_t)b * NB + bk];
    int x = tot;
#pragma unroll
    for (int off = 1; off < 64; off <<= 1) {
        int y = __shfl_up(x, off, 64);
        if (lane >= off) x += y;
    }
    __shared__ int wt[8];
    if (lane == 63) wt[wid] = x;
    __syncthreads();
    int wb = 0;
#pragma unroll
    for (int w = 0; w < 8; w++) if (w < wid) wb += wt[w];
    int start = wb + x - tot;
    bstart[bk] = start;
    if (bk == NB - 1) bstart[NB] = start + tot;
    unsigned run = (unsigned)start;
    for (int b = 0; b < B_CHUNKS; b++) {
        unsigned c = hcnt[(size_t)b * NB + bk];
        hcnt[(size_t)b * NB + bk] = run;
        run += c;
    }
}

// scatter edges into bucket-grouped u32 pairs (src<<8 | dst_local); runs are
// contiguous so stores cover mostly-full lines -> ~1x write amplification
__global__ __launch_bounds__(256) void k_bscatter(
    const int* __restrict__ src, const int* __restrict__ dst,
    const unsigned* __restrict__ hcnt, unsigned* __restrict__ pairs) {
    __shared__ unsigned cur[NB];
    for (int i = threadIdx.x; i < NB; i += 256)
        cur[i] = hcnt[(size_t)blockIdx.x * NB + i];
    __syncthreads();
    int base = blockIdx.x * CHUNK_E;
    for (int i = threadIdx.x; i < CHUNK_E; i += 256) {
        int e = base + i;
        int d = dst[e];
        int bk = d / BK_NODES;
        unsigned pos = atomicAdd(&cur[bk], 1u);
        pairs[pos] = ((unsigned)src[e] << 8) | (unsigned)(d - bk * BK_NODES);
    }
}

// one block per bucket: LDS counting-sort by dst, coalesced csr write,
// emit rs/re/dinv for the bucket's 196 nodes
__global__ __launch_bounds__(256) void k_bsort(
    const unsigned* __restrict__ pairs, const int* __restrict__ bstart,
    int* __restrict__ csr, int* __restrict__ rs, int* __restrict__ re,
    float* __restrict__ dinv) {
    __shared__ unsigned lp[BK_CAP];
    __shared__ unsigned cnt[BK_NODES];
    __shared__ unsigned rstart[BK_NODES];
    int bk = blockIdx.x;
    int s0 = bstart[bk], s1 = bstart[bk + 1];
    int ne = s1 - s0;
    if (ne > BK_CAP) ne = BK_CAP;            // statistically impossible guard
    for (int i = threadIdx.x; i < ne; i += 256) lp[i] = pairs[s0 + i];
    for (int i = threadIdx.x; i < BK_NODES; i += 256) cnt[i] = 0u;
    __syncthreads();
    for (int i = threadIdx.x; i < ne; i += 256)
        atomicAdd(&cnt[lp[i] & 0xffu], 1u);
    __syncthreads();
    // exclusive scan of cnt[196] on wave 0 (4 elems/lane)
    if (threadIdx.x < 64) {
        int lane = threadIdx.x;
        unsigned loc[4];
        unsigned s = 0;
#pragma unroll
        for (int q = 0; q < 4; q++) {
            int idx = lane * 4 + q;
            unsigned c = (idx < BK_NODES) ? cnt[idx] : 0u;
            loc[q] = s; s += c;
        }
        unsigned x = s;
#pragma unroll
        for (int off = 1; off < 64; off <<= 1) {
            unsigned y = __shfl_up((int)x, off, 64);
            if (lane >= off) x += y;
        }
        unsigned basev = x - s;
#pragma unroll
        for (int q = 0; q < 4; q++) {
            int idx = lane * 4 + q;
            if (idx < BK_NODES) rstart[idx] = basev + loc[q];
        }
    }
    __syncthreads();
    int nlo = bk * BK_NODES;
    for (int i = threadIdx.x; i < BK_NODES; i += 256) {
        int n = nlo + i;
        unsigned st = rstart[i];
        rs[n] = s0 + (int)st;
        re[n] = s0 + (int)(st + cnt[i]);
        dinv[n] = rsqrtf((float)(cnt[i] + 1));
    }
    __syncthreads();
    for (int i = threadIdx.x; i < ne; i += 256) {
        unsigned p = lp[i];
        unsigned pos = atomicAdd(&rstart[p & 0xffu], 1u);
        csr[s0 + (int)pos] = (int)(p >> 8);
    }
}

// ---- dense phase: h1b[n] = bf16( dinv[n] * (x[n] @ W1) ) ------------------

__global__ void k_lin1s(const float* __restrict__ x, const float* __restrict__ W1,
                        const float* __restrict__ dinv, unsigned* __restrict__ h1b) {
    __shared__ float w[IN_DIM * HID];
    for (int i = threadIdx.x; i < IN_DIM * HID; i += blockDim.x) w[i] = W1[i];
    __syncthreads();
    int n = blockIdx.x * blockDim.x + threadIdx.x;
    if (n >= N_NODES) return;
    float acc[HID];
#pragma unroll
    for (int j = 0; j < HID; j++) acc[j] = 0.f;
    const float4* xr = (const float4*)(x + (size_t)n * IN_DIM);
#pragma unroll
    for (int k4 = 0; k4 < IN_DIM / 4; k4++) {
        float4 v = xr[k4];
#pragma unroll
        for (int j = 0; j < HID; j++) {
            acc[j] += v.x * w[(k4 * 4 + 0) * HID + j]
                    + v.y * w[(k4 * 4 + 1) * HID + j]
                    + v.z * w[(k4 * 4 + 2) * HID + j]
                    + v.w * w[(k4 * 4 + 3) * HID + j];
        }
    }
    float di = dinv[n];
    uint4 o0, o1;
    o0.x = packbf2(di * acc[0],  di * acc[1]);
    o0.y = packbf2(di * acc[2],  di * acc[3]);
    o0.z = packbf2(di * acc[4],  di * acc[5]);
    o0.w = packbf2(di * acc[6],  di * acc[7]);
    o1.x = packbf2(di * acc[8],  di * acc[9]);
    o1.y = packbf2(di * acc[10], di * acc[11]);
    o1.z = packbf2(di * acc[12], di * acc[13]);
    o1.w = packbf2(di * acc[14], di * acc[15]);
    uint4* o = (uint4*)(h1b + (size_t)n * 8);
    o[0] = o0;
    o[1] = o1;
}

// pull layer 1: one wave per node, lanes=[8 edge-slots x 8 u32-words];
// h1b table is 3.2 MB -> L2-resident, 32 B per edge gather
__global__ __launch_bounds__(256) void k_pull1(
    const int* __restrict__ rs, const int* __restrict__ re,
    const int* __restrict__ csr, const unsigned* __restrict__ h1b,
    const float* __restrict__ dinv, const float* __restrict__ b1,
    const float* __restrict__ W2, float* __restrict__ h2s) {
    int n = blockIdx.x * 4 + (threadIdx.x >> 6);
    if (n >= N_NODES) return;
    int lane = threadIdx.x & 63;
    int slot = lane >> 3, w = lane & 7;
    int beg = rs[n], end = re[n];
    float a0 = 0.f, a1 = 0.f;
    for (int i = beg + slot; i < end; i += 8) {
        int s = csr[i];
        unsigned u = h1b[(size_t)s * 8 + w];
        a0 += __uint_as_float(u << 16);
        a1 += __uint_as_float(u & 0xffff0000u);
    }
    a0 += __shfl_xor(a0, 8, 64);  a1 += __shfl_xor(a1, 8, 64);
    a0 += __shfl_xor(a0, 16, 64); a1 += __shfl_xor(a1, 16, 64);
    a0 += __shfl_xor(a0, 32, 64); a1 += __shfl_xor(a1, 32, 64);
    unsigned us = h1b[(size_t)n * 8 + w];            // self-loop term
    a0 += __uint_as_float(us << 16);
    a1 += __uint_as_float(us & 0xffff0000u);
    float di = dinv[n];
    int j0 = 2 * w, j1 = 2 * w + 1;
    float v0 = fmaxf(di * a0 + b1[j0], 0.f);
    float v1 = fmaxf(di * a1 + b1[j1], 0.f);
    float p0 = v0 * W2[j0 * 2 + 0] + v1 * W2[j1 * 2 + 0];
    float p1 = v0 * W2[j0 * 2 + 1] + v1 * W2[j1 * 2 + 1];
    p0 += __shfl_xor(p0, 1, 64); p1 += __shfl_xor(p1, 1, 64);
    p0 += __shfl_xor(p0, 2, 64); p1 += __shfl_xor(p1, 2, 64);
    p0 += __shfl_xor(p0, 4, 64); p1 += __shfl_xor(p1, 4, 64);
    if (lane == 0) *(float2*)(h2s + (size_t)n * 2) = make_float2(di * p0, di * p1);
}

// pull layer 2, fused log_softmax: one wave per node, lanes=[32 edges x 2 feats]
__global__ __launch_bounds__(256) void k_pull2(
    const int* __restrict__ rs, const int* __restrict__ re,
    const int* __restrict__ csr, const float* __restrict__ h2s,
    const float* __restrict__ dinv, const float* __restrict__ b2,
    float* __restrict__ out) {
    int n = blockIdx.x * 4 + (threadIdx.x >> 6);
    if (n >= N_NODES) return;
    int lane = threadIdx.x & 63;
    int e = lane >> 1, k = lane & 1;
    int beg = rs[n], end = re[n];
    float acc = 0.f;
    for (int i = beg + e; i < end; i += 32) {
        int s = csr[i];
        acc += h2s[(size_t)s * 2 + k];
    }
#pragma unroll
    for (int m = 2; m <= 32; m <<= 1) acc += __shfl_xor(acc, m, 64);
    float di = dinv[n];
    float o = di * (acc + h2s[(size_t)n * 2 + k]) + b2[k];
    float other = __shfl_xor(o, 1, 64);
    float mx = fmaxf(o, other);
    float lse = mx + logf(expf(o - mx) + expf(other - mx));
    if (lane < 2) out[(size_t)n * 2 + k] = o - lse;
}

extern "C" void kernel_launch(void* const* d_in, const int* in_sizes, int n_in,
                              void* d_out, int out_size, void* d_ws, size_t ws_size,
                              hipStream_t stream) {
    const float* x  = (const float*)d_in[0];
    const int*   ei = (const int*)d_in[1];
    const int*   srcv = ei;
    const int*   dstv = ei + N_EDGES;
    const float* W1 = (const float*)d_in[2];
    const float* b1 = (const float*)d_in[3];
    const float* W2 = (const float*)d_in[4];
    const float* b2 = (const float*)d_in[5];
    float* out = (float*)d_out;

    float*    ws     = (float*)d_ws;
    float*    dinv   = ws + OFF_DINV;
    int*      rs     = (int*)(ws + OFF_RS);
    int*      re     = (int*)(ws + OFF_RE);
    unsigned* h1b    = (unsigned*)(ws + OFF_H1B);
    float*    h2s    = ws + OFF_H2;
    int*      csr    = (int*)(ws + OFF_CSR);
    unsigned* pairs  = (unsigned*)(ws + OFF_PAIRS);
    unsigned* hcnt   = (unsigned*)(ws + OFF_HCNT);
    int*      bstart = (int*)(ws + OFF_BST);

    k_bhist<<<B_CHUNKS, 256, 0, stream>>>(dstv, hcnt);
    k_bscan<<<1, 512, 0, stream>>>(hcnt, bstart);
    k_bscatter<<<B_CHUNKS, 256, 0, stream>>>(srcv, dstv, hcnt, pairs);
    k_bsort<<<NB, 256, 0, stream>>>(pairs, bstart, csr, rs, re, dinv);
    k_lin1s<<<(N_NODES + 255) / 256, 256, 0, stream>>>(x, W1, dinv, h1b);
    k_pull1<<<(N_NODES + 3) / 4, 256, 0, stream>>>(rs, re, csr, h1b, dinv, b1, W2, h2s);
    k_pull2<<<(N_NODES + 3) / 4, 256, 0, stream>>>(rs, re, csr, h2s, dinv, b2, out);
}

// Round 15
// 380.671 us; speedup vs baseline: 1.0416x; 1.0416x over previous
//
#include <hip/hip_runtime.h>
#include <math.h>
#include <stdint.h>

#define N_NODES 100000
#define N_EDGES 3200000
#define IN_DIM  64
#define HID     16
#define OUTD    2

#define NPAD     100352                // N padded (multiple of 1024)
#define B_CHUNKS 128                   // edge chunks
#define CHUNK_E  (N_EDGES / B_CHUNKS)  // 25000 edges per chunk
#define NB       512                   // dst buckets
#define BK_NODES (NPAD / NB)           // 196 nodes per bucket
#define BK_CAP   7680                  // mean 6250 + ~18 sigma, LDS cap

// workspace layout (float offsets) — ~31 MB
#define OFF_DINV  0
#define OFF_RS    (OFF_DINV + NPAD)
#define OFF_RE    (OFF_RS + NPAD)
#define OFF_H1B   (OFF_RE + NPAD)            // bf16x2-packed h1s [N][8] u32 (3.2 MB)
#define OFF_H2    (OFF_H1B + N_NODES * 8)    // h2s = dinv[n]*h2raw  [N,2] fp32
#define OFF_CSR   (OFF_H2 + N_NODES * OUTD)  // CSR src ids [E]
#define OFF_PAIRS (OFF_CSR + N_EDGES)        // u32 (src<<8 | dst_local) [E]
#define OFF_HCNT  (OFF_PAIRS + N_EDGES)      // u32 [B_CHUNKS][NB]
#define OFF_BST   (OFF_HCNT + B_CHUNKS * NB) // int [NB+1]

__device__ __forceinline__ unsigned packbf2(float f0, float f1) {
    unsigned a = __float_as_uint(f0), b = __float_as_uint(f1);
    a = (a + 0x7fffu + ((a >> 16) & 1u)) >> 16;          // RNE
    b = (b + 0x7fffu + ((b >> 16) & 1u)) >> 16;
    return a | (b << 16);
}

// ---- CSR build: zero global atomics, ~1x write amplification --------------

__global__ __launch_bounds__(256) void k_bhist(const int* __restrict__ dst,
                                               unsigned* __restrict__ hcnt) {
    __shared__ unsigned h[NB];
    for (int i = threadIdx.x; i < NB; i += 256) h[i] = 0u;
    __syncthreads();
    int base = blockIdx.x * CHUNK_E;
    for (int i = threadIdx.x; i < CHUNK_E; i += 256)
        atomicAdd(&h[dst[base + i] / BK_NODES], 1u);
    __syncthreads();
    for (int i = threadIdx.x; i < NB; i += 256)
        hcnt[(size_t)blockIdx.x * NB + i] = h[i];
}

// bucket starts + in-place chunk-prefix: hcnt[b][bk] -> absolute run base
__global__ __launch_bounds__(512) void k_bscan(unsigned* __restrict__ hcnt,
                                               int* __restrict__ bstart) {
    int bk = threadIdx.x, lane = bk & 63, wid = bk >> 6;
    int tot = 0;
    for (int b = 0; b < B_CHUNKS; b++) tot += (int)hcnt[(size_t)b * NB + bk];
    int x = tot;
#pragma unroll
    for (int off = 1; off < 64; off <<= 1) {
        int y = __shfl_up(x, off, 64);
        if (lane >= off) x += y;
    }
    __shared__ int wt[8];
    if (lane == 63) wt[wid] = x;
    __syncthreads();
    int wb = 0;
#pragma unroll
    for (int w = 0; w < 8; w++) if (w < wid) wb += wt[w];
    int start = wb + x - tot;
    bstart[bk] = start;
    if (bk == NB - 1) bstart[NB] = start + tot;
    unsigned run = (unsigned)start;
    for (int b = 0; b < B_CHUNKS; b++) {
        unsigned c = hcnt[(size_t)b * NB + bk];
        hcnt[(size_t)b * NB + bk] = run;
        run += c;
    }
}

// scatter edges into bucket-grouped u32 pairs (src<<8 | dst_local); runs are
// contiguous so stores cover mostly-full lines -> ~1x write amplification
__global__ __launch_bounds__(256) void k_bscatter(
    const int* __restrict__ src, const int* __restrict__ dst,
    const unsigned* __restrict__ hcnt, unsigned* __restrict__ pairs) {
    __shared__ unsigned cur[NB];
    for (int i = threadIdx.x; i < NB; i += 256)
        cur[i] = hcnt[(size_t)blockIdx.x * NB + i];
    __syncthreads();
    int base = blockIdx.x * CHUNK_E;
    for (int i = threadIdx.x; i < CHUNK_E; i += 256) {
        int e = base + i;
        int d = dst[e];
        int bk = d / BK_NODES;
        unsigned pos = atomicAdd(&cur[bk], 1u);
        pairs[pos] = ((unsigned)src[e] << 8) | (unsigned)(d - bk * BK_NODES);
    }
}

// one block per bucket: LDS counting-sort by dst, coalesced csr write,
// emit rs/re/dinv for the bucket's 196 nodes
__global__ __launch_bounds__(256) void k_bsort(
    const unsigned* __restrict__ pairs, const int* __restrict__ bstart,
    int* __restrict__ csr, int* __restrict__ rs, int* __restrict__ re,
    float* __restrict__ dinv) {
    __shared__ unsigned lp[BK_CAP];
    __shared__ unsigned cnt[BK_NODES];
    __shared__ unsigned rstart[BK_NODES];
    int bk = blockIdx.x;
    int s0 = bstart[bk], s1 = bstart[bk + 1];
    int ne = s1 - s0;
    if (ne > BK_CAP) ne = BK_CAP;            // statistically impossible guard
    for (int i = threadIdx.x; i < ne; i += 256) lp[i] = pairs[s0 + i];
    for (int i = threadIdx.x; i < BK_NODES; i += 256) cnt[i] = 0u;
    __syncthreads();
    for (int i = threadIdx.x; i < ne; i += 256)
        atomicAdd(&cnt[lp[i] & 0xffu], 1u);
    __syncthreads();
    // exclusive scan of cnt[196] on wave 0 (4 elems/lane)
    if (threadIdx.x < 64) {
        int lane = threadIdx.x;
        unsigned loc[4];
        unsigned s = 0;
#pragma unroll
        for (int q = 0; q < 4; q++) {
            int idx = lane * 4 + q;
            unsigned c = (idx < BK_NODES) ? cnt[idx] : 0u;
            loc[q] = s; s += c;
        }
        unsigned x = s;
#pragma unroll
        for (int off = 1; off < 64; off <<= 1) {
            unsigned y = __shfl_up((int)x, off, 64);
            if (lane >= off) x += y;
        }
        unsigned basev = x - s;
#pragma unroll
        for (int q = 0; q < 4; q++) {
            int idx = lane * 4 + q;
            if (idx < BK_NODES) rstart[idx] = basev + loc[q];
        }
    }
    __syncthreads();
    int nlo = bk * BK_NODES;
    for (int i = threadIdx.x; i < BK_NODES; i += 256) {
        int n = nlo + i;
        unsigned st = rstart[i];
        rs[n] = s0 + (int)st;
        re[n] = s0 + (int)(st + cnt[i]);
        dinv[n] = rsqrtf((float)(cnt[i] + 1));
    }
    __syncthreads();
    for (int i = threadIdx.x; i < ne; i += 256) {
        unsigned p = lp[i];
        unsigned pos = atomicAdd(&rstart[p & 0xffu], 1u);
        csr[s0 + (int)pos] = (int)(p >> 8);
    }
}

// ---- dense phase: h1b[n] = bf16( dinv[n] * (x[n] @ W1) ) ------------------
// __launch_bounds__(256, 4): 4 waves/EU -> VGPR cap 128, prevents the
// occupancy heuristic from throttling to 64 VGPR and spilling acc[] to
// scratch (r12: FETCH 90MB/WRITE 142MB vs 26/3.2 expected = spill traffic)

__global__ __launch_bounds__(256, 4) void k_lin1s(
    const float* __restrict__ x, const float* __restrict__ W1,
    const float* __restrict__ dinv, unsigned* __restrict__ h1b) {
    __shared__ float w[IN_DIM * HID];
    for (int i = threadIdx.x; i < IN_DIM * HID; i += blockDim.x) w[i] = W1[i];
    __syncthreads();
    int n = blockIdx.x * blockDim.x + threadIdx.x;
    if (n >= N_NODES) return;
    float acc[HID];
#pragma unroll
    for (int j = 0; j < HID; j++) acc[j] = 0.f;
    const float4* xr = (const float4*)(x + (size_t)n * IN_DIM);
#pragma unroll
    for (int k4 = 0; k4 < IN_DIM / 4; k4++) {
        float4 v = xr[k4];
#pragma unroll
        for (int j = 0; j < HID; j++) {
            acc[j] += v.x * w[(k4 * 4 + 0) * HID + j]
                    + v.y * w[(k4 * 4 + 1) * HID + j]
                    + v.z * w[(k4 * 4 + 2) * HID + j]
                    + v.w * w[(k4 * 4 + 3) * HID + j];
        }
    }
    float di = dinv[n];
    uint4 o0, o1;
    o0.x = packbf2(di * acc[0],  di * acc[1]);
    o0.y = packbf2(di * acc[2],  di * acc[3]);
    o0.z = packbf2(di * acc[4],  di * acc[5]);
    o0.w = packbf2(di * acc[6],  di * acc[7]);
    o1.x = packbf2(di * acc[8],  di * acc[9]);
    o1.y = packbf2(di * acc[10], di * acc[11]);
    o1.z = packbf2(di * acc[12], di * acc[13]);
    o1.w = packbf2(di * acc[14], di * acc[15]);
    uint4* o = (uint4*)(h1b + (size_t)n * 8);
    o[0] = o0;
    o[1] = o1;
}

// pull layer 1: one wave per node, lanes=[8 edge-slots x 8 u32-words];
// h1b table is 3.2 MB -> L2-resident, 32 B per edge gather
__global__ __launch_bounds__(256) void k_pull1(
    const int* __restrict__ rs, const int* __restrict__ re,
    const int* __restrict__ csr, const unsigned* __restrict__ h1b,
    const float* __restrict__ dinv, const float* __restrict__ b1,
    const float* __restrict__ W2, float* __restrict__ h2s) {
    int n = blockIdx.x * 4 + (threadIdx.x >> 6);
    if (n >= N_NODES) return;
    int lane = threadIdx.x & 63;
    int slot = lane >> 3, w = lane & 7;
    int beg = rs[n], end = re[n];
    float a0 = 0.f, a1 = 0.f;
    for (int i = beg + slot; i < end; i += 8) {
        int s = csr[i];
        unsigned u = h1b[(size_t)s * 8 + w];
        a0 += __uint_as_float(u << 16);
        a1 += __uint_as_float(u & 0xffff0000u);
    }
    a0 += __shfl_xor(a0, 8, 64);  a1 += __shfl_xor(a1, 8, 64);
    a0 += __shfl_xor(a0, 16, 64); a1 += __shfl_xor(a1, 16, 64);
    a0 += __shfl_xor(a0, 32, 64); a1 += __shfl_xor(a1, 32, 64);
    unsigned us = h1b[(size_t)n * 8 + w];            // self-loop term
    a0 += __uint_as_float(us << 16);
    a1 += __uint_as_float(us & 0xffff0000u);
    float di = dinv[n];
    int j0 = 2 * w, j1 = 2 * w + 1;
    float v0 = fmaxf(di * a0 + b1[j0], 0.f);
    float v1 = fmaxf(di * a1 + b1[j1], 0.f);
    float p0 = v0 * W2[j0 * 2 + 0] + v1 * W2[j1 * 2 + 0];
    float p1 = v0 * W2[j0 * 2 + 1] + v1 * W2[j1 * 2 + 1];
    p0 += __shfl_xor(p0, 1, 64); p1 += __shfl_xor(p1, 1, 64);
    p0 += __shfl_xor(p0, 2, 64); p1 += __shfl_xor(p1, 2, 64);
    p0 += __shfl_xor(p0, 4, 64); p1 += __shfl_xor(p1, 4, 64);
    if (lane == 0) *(float2*)(h2s + (size_t)n * 2) = make_float2(di * p0, di * p1);
}

// pull layer 2, fused log_softmax: one wave per node, lanes=[32 edges x 2 feats]
__global__ __launch_bounds__(256) void k_pull2(
    const int* __restrict__ rs, const int* __restrict__ re,
    const int* __restrict__ csr, const float* __restrict__ h2s,
    const float* __restrict__ dinv, const float* __restrict__ b2,
    float* __restrict__ out) {
    int n = blockIdx.x * 4 + (threadIdx.x >> 6);
    if (n >= N_NODES) return;
    int lane = threadIdx.x & 63;
    int e = lane >> 1, k = lane & 1;
    int beg = rs[n], end = re[n];
    float acc = 0.f;
    for (int i = beg + e; i < end; i += 32) {
        int s = csr[i];
        acc += h2s[(size_t)s * 2 + k];
    }
#pragma unroll
    for (int m = 2; m <= 32; m <<= 1) acc += __shfl_xor(acc, m, 64);
    float di = dinv[n];
    float o = di * (acc + h2s[(size_t)n * 2 + k]) + b2[k];
    float other = __shfl_xor(o, 1, 64);
    float mx = fmaxf(o, other);
    float lse = mx + logf(expf(o - mx) + expf(other - mx));
    if (lane < 2) out[(size_t)n * 2 + k] = o - lse;
}

extern "C" void kernel_launch(void* const* d_in, const int* in_sizes, int n_in,
                              void* d_out, int out_size, void* d_ws, size_t ws_size,
                              hipStream_t stream) {
    const float* x  = (const float*)d_in[0];
    const int*   ei = (const int*)d_in[1];
    const int*   srcv = ei;
    const int*   dstv = ei + N_EDGES;
    const float* W1 = (const float*)d_in[2];
    const float* b1 = (const float*)d_in[3];
    const float* W2 = (const float*)d_in[4];
    const float* b2 = (const float*)d_in[5];
    float* out = (float*)d_out;

    float*    ws     = (float*)d_ws;
    float*    dinv   = ws + OFF_DINV;
    int*      rs     = (int*)(ws + OFF_RS);
    int*      re     = (int*)(ws + OFF_RE);
    unsigned* h1b    = (unsigned*)(ws + OFF_H1B);
    float*    h2s    = ws + OFF_H2;
    int*      csr    = (int*)(ws + OFF_CSR);
    unsigned* pairs  = (unsigned*)(ws + OFF_PAIRS);
    unsigned* hcnt   = (unsigned*)(ws + OFF_HCNT);
    int*      bstart = (int*)(ws + OFF_BST);

    k_bhist<<<B_CHUNKS, 256, 0, stream>>>(dstv, hcnt);
    k_bscan<<<1, 512, 0, stream>>>(hcnt, bstart);
    k_bscatter<<<B_CHUNKS, 256, 0, stream>>>(srcv, dstv, hcnt, pairs);
    k_bsort<<<NB, 256, 0, stream>>>(pairs, bstart, csr, rs, re, dinv);
    k_lin1s<<<(N_NODES + 255) / 256, 256, 0, stream>>>(x, W1, dinv, h1b);
    k_pull1<<<(N_NODES + 3) / 4, 256, 0, stream>>>(rs, re, csr, h1b, dinv, b1, W2, h2s);
    k_pull2<<<(N_NODES + 3) / 4, 256, 0, stream>>>(rs, re, csr, h2s, dinv, b2, out);
}

// Round 16
// 288.247 us; speedup vs baseline: 1.3755x; 1.3206x over previous
//
#include <hip/hip_runtime.h>
#include <math.h>
#include <stdint.h>

#define N_NODES 100000
#define N_EDGES 3200000
#define IN_DIM  64
#define HID     16
#define OUTD    2

#define NPAD     100352                // N padded (multiple of 1024)
#define B_CHUNKS 128                   // edge chunks
#define CHUNK_E  (N_EDGES / B_CHUNKS)  // 25000 edges per chunk
#define NB       512                   // dst buckets
#define BK_NODES (NPAD / NB)           // 196 nodes per bucket
#define BK_CAP   7680                  // mean 6250 + ~18 sigma, LDS cap

// workspace layout (float offsets) — ~31 MB
#define OFF_DINV  0
#define OFF_RS    (OFF_DINV + NPAD)
#define OFF_RE    (OFF_RS + NPAD)
#define OFF_H1B   (OFF_RE + NPAD)            // bf16x2-packed h1s [N][8] u32 (3.2 MB)
#define OFF_H2    (OFF_H1B + N_NODES * 8)    // h2s = dinv[n]*h2raw  [N,2] fp32
#define OFF_CSR   (OFF_H2 + N_NODES * OUTD)  // CSR src ids [E]
#define OFF_PAIRS (OFF_CSR + N_EDGES)        // u32 (src<<8 | dst_local) [E]
#define OFF_HCNT  (OFF_PAIRS + N_EDGES)      // u32 [B_CHUNKS][NB]
#define OFF_BST   (OFF_HCNT + B_CHUNKS * NB) // int [NB+1]

__device__ __forceinline__ unsigned packbf2(float f0, float f1) {
    unsigned a = __float_as_uint(f0), b = __float_as_uint(f1);
    a = (a + 0x7fffu + ((a >> 16) & 1u)) >> 16;          // RNE
    b = (b + 0x7fffu + ((b >> 16) & 1u)) >> 16;
    return a | (b << 16);
}

// ---- CSR build: zero global atomics, ~1x write amplification --------------

__global__ __launch_bounds__(256) void k_bhist(const int* __restrict__ dst,
                                               unsigned* __restrict__ hcnt) {
    __shared__ unsigned h[NB];
    for (int i = threadIdx.x; i < NB; i += 256) h[i] = 0u;
    __syncthreads();
    int base = blockIdx.x * CHUNK_E;
    for (int i = threadIdx.x; i < CHUNK_E; i += 256)
        atomicAdd(&h[dst[base + i] / BK_NODES], 1u);
    __syncthreads();
    for (int i = threadIdx.x; i < NB; i += 256)
        hcnt[(size_t)blockIdx.x * NB + i] = h[i];
}

// bucket starts + in-place chunk-prefix: hcnt[b][bk] -> absolute run base
__global__ __launch_bounds__(512) void k_bscan(unsigned* __restrict__ hcnt,
                                               int* __restrict__ bstart) {
    int bk = threadIdx.x, lane = bk & 63, wid = bk >> 6;
    int tot = 0;
    for (int b = 0; b < B_CHUNKS; b++) tot += (int)hcnt[(size_t)b * NB + bk];
    int x = tot;
#pragma unroll
    for (int off = 1; off < 64; off <<= 1) {
        int y = __shfl_up(x, off, 64);
        if (lane >= off) x += y;
    }
    __shared__ int wt[8];
    if (lane == 63) wt[wid] = x;
    __syncthreads();
    int wb = 0;
#pragma unroll
    for (int w = 0; w < 8; w++) if (w < wid) wb += wt[w];
    int start = wb + x - tot;
    bstart[bk] = start;
    if (bk == NB - 1) bstart[NB] = start + tot;
    unsigned run = (unsigned)start;
    for (int b = 0; b < B_CHUNKS; b++) {
        unsigned c = hcnt[(size_t)b * NB + bk];
        hcnt[(size_t)b * NB + bk] = run;
        run += c;
    }
}

// scatter edges into bucket-grouped u32 pairs (src<<8 | dst_local); runs are
// contiguous so stores cover mostly-full lines -> ~1x write amplification
__global__ __launch_bounds__(256) void k_bscatter(
    const int* __restrict__ src, const int* __restrict__ dst,
    const unsigned* __restrict__ hcnt, unsigned* __restrict__ pairs) {
    __shared__ unsigned cur[NB];
    for (int i = threadIdx.x; i < NB; i += 256)
        cur[i] = hcnt[(size_t)blockIdx.x * NB + i];
    __syncthreads();
    int base = blockIdx.x * CHUNK_E;
    for (int i = threadIdx.x; i < CHUNK_E; i += 256) {
        int e = base + i;
        int d = dst[e];
        int bk = d / BK_NODES;
        unsigned pos = atomicAdd(&cur[bk], 1u);
        pairs[pos] = ((unsigned)src[e] << 8) | (unsigned)(d - bk * BK_NODES);
    }
}

// one block per bucket: LDS counting-sort by dst, coalesced csr write,
// emit rs/re/dinv for the bucket's 196 nodes
__global__ __launch_bounds__(256) void k_bsort(
    const unsigned* __restrict__ pairs, const int* __restrict__ bstart,
    int* __restrict__ csr, int* __restrict__ rs, int* __restrict__ re,
    float* __restrict__ dinv) {
    __shared__ unsigned lp[BK_CAP];
    __shared__ unsigned cnt[BK_NODES];
    __shared__ unsigned rstart[BK_NODES];
    int bk = blockIdx.x;
    int s0 = bstart[bk], s1 = bstart[bk + 1];
    int ne = s1 - s0;
    if (ne > BK_CAP) ne = BK_CAP;            // statistically impossible guard
    for (int i = threadIdx.x; i < ne; i += 256) lp[i] = pairs[s0 + i];
    for (int i = threadIdx.x; i < BK_NODES; i += 256) cnt[i] = 0u;
    __syncthreads();
    for (int i = threadIdx.x; i < ne; i += 256)
        atomicAdd(&cnt[lp[i] & 0xffu], 1u);
    __syncthreads();
    // exclusive scan of cnt[196] on wave 0 (4 elems/lane)
    if (threadIdx.x < 64) {
        int lane = threadIdx.x;
        unsigned loc[4];
        unsigned s = 0;
#pragma unroll
        for (int q = 0; q < 4; q++) {
            int idx = lane * 4 + q;
            unsigned c = (idx < BK_NODES) ? cnt[idx] : 0u;
            loc[q] = s; s += c;
        }
        unsigned x = s;
#pragma unroll
        for (int off = 1; off < 64; off <<= 1) {
            unsigned y = __shfl_up((int)x, off, 64);
            if (lane >= off) x += y;
        }
        unsigned basev = x - s;
#pragma unroll
        for (int q = 0; q < 4; q++) {
            int idx = lane * 4 + q;
            if (idx < BK_NODES) rstart[idx] = basev + loc[q];
        }
    }
    __syncthreads();
    int nlo = bk * BK_NODES;
    for (int i = threadIdx.x; i < BK_NODES; i += 256) {
        int n = nlo + i;
        unsigned st = rstart[i];
        rs[n] = s0 + (int)st;
        re[n] = s0 + (int)(st + cnt[i]);
        dinv[n] = rsqrtf((float)(cnt[i] + 1));
    }
    __syncthreads();
    for (int i = threadIdx.x; i < ne; i += 256) {
        unsigned p = lp[i];
        unsigned pos = atomicAdd(&rstart[p & 0xffu], 1u);
        csr[s0 + (int)pos] = (int)(p >> 8);
    }
}

// ---- dense phase: h1b[n] = bf16( dinv[n] * (x[n] @ W1) ) ------------------
// r15 post-mortem: launch_bounds(256,4) did NOT raise VGPR cap (still 64) and
// the 139MB excess WRITE persisted. Structural fix instead: 2 threads/node,
// 8 features each -> acc[8], ~25 VGPR demand, spill impossible at 64.
// Lane pairs read the same x row (same-address broadcast); each thread
// writes exactly one coalesced uint4 at h1b[t] (t = n*2 + half).

__global__ __launch_bounds__(256) void k_lin1s(
    const float* __restrict__ x, const float* __restrict__ W1,
    const float* __restrict__ dinv, unsigned* __restrict__ h1b) {
    __shared__ float w[IN_DIM * HID];
    for (int i = threadIdx.x; i < IN_DIM * HID; i += 256) w[i] = W1[i];
    __syncthreads();
    int t = blockIdx.x * 256 + threadIdx.x;
    int n = t >> 1;
    if (n >= N_NODES) return;
    int half = t & 1;
    float acc[8];
#pragma unroll
    for (int j = 0; j < 8; j++) acc[j] = 0.f;
    const float4* xr = (const float4*)(x + (size_t)n * IN_DIM);
    const float* wh = w + half * 8;
#pragma unroll
    for (int k4 = 0; k4 < IN_DIM / 4; k4++) {
        float4 v = xr[k4];
#pragma unroll
        for (int j = 0; j < 8; j++) {
            acc[j] += v.x * wh[(k4 * 4 + 0) * HID + j]
                    + v.y * wh[(k4 * 4 + 1) * HID + j]
                    + v.z * wh[(k4 * 4 + 2) * HID + j]
                    + v.w * wh[(k4 * 4 + 3) * HID + j];
        }
    }
    float di = dinv[n];
    uint4 o;
    o.x = packbf2(di * acc[0], di * acc[1]);
    o.y = packbf2(di * acc[2], di * acc[3]);
    o.z = packbf2(di * acc[4], di * acc[5]);
    o.w = packbf2(di * acc[6], di * acc[7]);
    ((uint4*)h1b)[t] = o;
}

// pull layer 1: one wave per node, lanes=[8 edge-slots x 8 u32-words];
// h1b table is 3.2 MB -> L2-resident, 32 B per edge gather
__global__ __launch_bounds__(256) void k_pull1(
    const int* __restrict__ rs, const int* __restrict__ re,
    const int* __restrict__ csr, const unsigned* __restrict__ h1b,
    const float* __restrict__ dinv, const float* __restrict__ b1,
    const float* __restrict__ W2, float* __restrict__ h2s) {
    int n = blockIdx.x * 4 + (threadIdx.x >> 6);
    if (n >= N_NODES) return;
    int lane = threadIdx.x & 63;
    int slot = lane >> 3, w = lane & 7;
    int beg = rs[n], end = re[n];
    float a0 = 0.f, a1 = 0.f;
    for (int i = beg + slot; i < end; i += 8) {
        int s = csr[i];
        unsigned u = h1b[(size_t)s * 8 + w];
        a0 += __uint_as_float(u << 16);
        a1 += __uint_as_float(u & 0xffff0000u);
    }
    a0 += __shfl_xor(a0, 8, 64);  a1 += __shfl_xor(a1, 8, 64);
    a0 += __shfl_xor(a0, 16, 64); a1 += __shfl_xor(a1, 16, 64);
    a0 += __shfl_xor(a0, 32, 64); a1 += __shfl_xor(a1, 32, 64);
    unsigned us = h1b[(size_t)n * 8 + w];            // self-loop term
    a0 += __uint_as_float(us << 16);
    a1 += __uint_as_float(us & 0xffff0000u);
    float di = dinv[n];
    int j0 = 2 * w, j1 = 2 * w + 1;
    float v0 = fmaxf(di * a0 + b1[j0], 0.f);
    float v1 = fmaxf(di * a1 + b1[j1], 0.f);
    float p0 = v0 * W2[j0 * 2 + 0] + v1 * W2[j1 * 2 + 0];
    float p1 = v0 * W2[j0 * 2 + 1] + v1 * W2[j1 * 2 + 1];
    p0 += __shfl_xor(p0, 1, 64); p1 += __shfl_xor(p1, 1, 64);
    p0 += __shfl_xor(p0, 2, 64); p1 += __shfl_xor(p1, 2, 64);
    p0 += __shfl_xor(p0, 4, 64); p1 += __shfl_xor(p1, 4, 64);
    if (lane == 0) *(float2*)(h2s + (size_t)n * 2) = make_float2(di * p0, di * p1);
}

// pull layer 2, fused log_softmax: one wave per node, lanes=[32 edges x 2 feats]
__global__ __launch_bounds__(256) void k_pull2(
    const int* __restrict__ rs, const int* __restrict__ re,
    const int* __restrict__ csr, const float* __restrict__ h2s,
    const float* __restrict__ dinv, const float* __restrict__ b2,
    float* __restrict__ out) {
    int n = blockIdx.x * 4 + (threadIdx.x >> 6);
    if (n >= N_NODES) return;
    int lane = threadIdx.x & 63;
    int e = lane >> 1, k = lane & 1;
    int beg = rs[n], end = re[n];
    float acc = 0.f;
    for (int i = beg + e; i < end; i += 32) {
        int s = csr[i];
        acc += h2s[(size_t)s * 2 + k];
    }
#pragma unroll
    for (int m = 2; m <= 32; m <<= 1) acc += __shfl_xor(acc, m, 64);
    float di = dinv[n];
    float o = di * (acc + h2s[(size_t)n * 2 + k]) + b2[k];
    float other = __shfl_xor(o, 1, 64);
    float mx = fmaxf(o, other);
    float lse = mx + logf(expf(o - mx) + expf(other - mx));
    if (lane < 2) out[(size_t)n * 2 + k] = o - lse;
}

extern "C" void kernel_launch(void* const* d_in, const int* in_sizes, int n_in,
                              void* d_out, int out_size, void* d_ws, size_t ws_size,
                              hipStream_t stream) {
    const float* x  = (const float*)d_in[0];
    const int*   ei = (const int*)d_in[1];
    const int*   srcv = ei;
    const int*   dstv = ei + N_EDGES;
    const float* W1 = (const float*)d_in[2];
    const float* b1 = (const float*)d_in[3];
    const float* W2 = (const float*)d_in[4];
    const float* b2 = (const float*)d_in[5];
    float* out = (float*)d_out;

    float*    ws     = (float*)d_ws;
    float*    dinv   = ws + OFF_DINV;
    int*      rs     = (int*)(ws + OFF_RS);
    int*      re     = (int*)(ws + OFF_RE);
    unsigned* h1b    = (unsigned*)(ws + OFF_H1B);
    float*    h2s    = ws + OFF_H2;
    int*      csr    = (int*)(ws + OFF_CSR);
    unsigned* pairs  = (unsigned*)(ws + OFF_PAIRS);
    unsigned* hcnt   = (unsigned*)(ws + OFF_HCNT);
    int*      bstart = (int*)(ws + OFF_BST);

    k_bhist<<<B_CHUNKS, 256, 0, stream>>>(dstv, hcnt);
    k_bscan<<<1, 512, 0, stream>>>(hcnt, bstart);
    k_bscatter<<<B_CHUNKS, 256, 0, stream>>>(srcv, dstv, hcnt, pairs);
    k_bsort<<<NB, 256, 0, stream>>>(pairs, bstart, csr, rs, re, dinv);
    k_lin1s<<<(2 * N_NODES + 255) / 256, 256, 0, stream>>>(x, W1, dinv, h1b);
    k_pull1<<<(N_NODES + 3) / 4, 256, 0, stream>>>(rs, re, csr, h1b, dinv, b1, W2, h2s);
    k_pull2<<<(N_NODES + 3) / 4, 256, 0, stream>>>(rs, re, csr, h2s, dinv, b2, out);
}